// Round 6
// baseline (1714.706 us; speedup 1.0000x reference)
//
#include <hip/hip_runtime.h>

#define NPTS 32768
#define BLOCK 256
#define SPT 16                            // source points per thread
#define NSLICE 128                        // target slices per direction
#define SLICE_PTS (NPTS / NSLICE)         // 256
#define SRC_PER_BLOCK (BLOCK * SPT)       // 4096
#define SRC_CHUNKS (NPTS / SRC_PER_BLOCK) // 8
#define GRID (2 * SRC_CHUNKS * NSLICE)    // 2048 blocks -> 8 blocks/CU, 32 waves/CU
#define SENTINEL 0x7F7F7F7Fu              // == 3.39e38f; memset pattern 0x7F
#define LASTVAL (SENTINEL + (unsigned)GRID - 1u)

// Pass 1: block = (dir, source-chunk of 4096, target-slice of 256).
// min_t |s-t|^2 = |s|^2 - 2 * max_t (s.t - |t|^2/2); qh = -|t|^2/2 staged in LDS.
// R4-proven inner loop: software-pipelined prefetch rotation, unroll 4.
// 8 waves/SIMD (launch_bounds 256,8) to hide LDS-return latency.
template <bool FUSED>
__global__ __launch_bounds__(BLOCK, 8)
void chamfer_pass1(const float* __restrict__ pred,
                   const float* __restrict__ targ,
                   unsigned int* __restrict__ mins,
                   unsigned int* __restrict__ counter,
                   float* __restrict__ out) {
    __shared__ float4 sh[SLICE_PTS + 2];   // +2: prefetch overrun pad (never consumed)

    int b = blockIdx.x;
    int dir = b >> 10;             // 0: pred->target, 1: target->pred
    int rem = b & 1023;
    int slice = rem >> 3;          // 0..127
    int chunk = rem & 7;           // 0..7

    const float* src = dir ? targ : pred;
    const float* tgt = dir ? pred : targ;
    unsigned int* outm = mins + dir * NPTS;

    // stage the target slice as {x, y, z, -|t|^2/2}
    int slice_base = slice * SLICE_PTS;
    {
        int j = threadIdx.x;               // SLICE_PTS == BLOCK
        int g = slice_base + j;
        float x = tgt[3*g+0], y = tgt[3*g+1], z = tgt[3*g+2];
        sh[j] = make_float4(x, y, z, -0.5f * (x*x + y*y + z*z));
    }

    // 16 source points in registers
    float sx[SPT], sy[SPT], sz[SPT], m[SPT];
    int i_base = chunk * SRC_PER_BLOCK + threadIdx.x;
    #pragma unroll
    for (int p = 0; p < SPT; ++p) {
        int i = i_base + p * BLOCK;
        sx[p] = src[3*i+0]; sy[p] = src[3*i+1]; sz[p] = src[3*i+2];
        m[p] = -3.4e38f;
    }
    __syncthreads();

    // software-pipelined: prefetch next target pair while computing current
    float4 ca = sh[0], cb = sh[1];
    #pragma unroll 4
    for (int j = 0; j < SLICE_PTS; j += 2) {
        float4 na = sh[j+2];       // pad makes last-iter read safe
        float4 nb = sh[j+3];
        #pragma unroll
        for (int p = 0; p < SPT; ++p) {
            float ra = fmaf(sx[p], ca.x, fmaf(sy[p], ca.y, fmaf(sz[p], ca.z, ca.w)));
            float rb = fmaf(sx[p], cb.x, fmaf(sy[p], cb.y, fmaf(sz[p], cb.z, cb.w)));
            m[p] = fmaxf(m[p], fmaxf(ra, rb));   // -> v_max3_f32
        }
        ca = na; cb = nb;
    }

    #pragma unroll
    for (int p = 0; p < SPT; ++p) {
        int i = i_base + p * BLOCK;
        float q = fmaf(sx[p], sx[p], fmaf(sy[p], sy[p], sz[p]*sz[p]));
        float d = fmaxf(fmaf(-2.0f, m[p], q), 0.0f);  // exact distance >= 0
        atomicMin(&outm[i], __float_as_uint(d));      // non-neg float: uint cmp ok
    }

    if (!FUSED) return;

    // ---- fused finalization: last block reduces ----
    __threadfence();   // release our mins updates device-wide
    __shared__ unsigned int is_last;
    if (threadIdx.x == 0)
        is_last = (atomicAdd(counter, 1u) == LASTVAL) ? 1u : 0u;
    __syncthreads();
    if (is_last) {
        __threadfence();   // acquire side
        float sum = 0.0f;
        for (int i = threadIdx.x; i < 2 * NPTS; i += BLOCK) {
            unsigned int u = __hip_atomic_load(&mins[i], __ATOMIC_RELAXED,
                                               __HIP_MEMORY_SCOPE_AGENT);
            sum += __uint_as_float(u);
        }
        #pragma unroll
        for (int off = 32; off > 0; off >>= 1)
            sum += __shfl_down(sum, off, 64);
        __shared__ float wsum[4];
        int lane = threadIdx.x & 63, wave = threadIdx.x >> 6;
        if (lane == 0) wsum[wave] = sum;
        __syncthreads();
        if (threadIdx.x == 0)
            out[0] = (wsum[0] + wsum[1] + wsum[2] + wsum[3]) * (1.0f / NPTS);
    }
}

// Fallback pass 2 (only used if ws_size can't hold the counter word).
__global__ __launch_bounds__(256)
void chamfer_pass2(const unsigned int* __restrict__ mins,
                   float* __restrict__ out) {
    float sum = 0.0f;
    for (int i = blockIdx.x * blockDim.x + threadIdx.x; i < 2 * NPTS;
         i += gridDim.x * blockDim.x)
        sum += __uint_as_float(mins[i]);
    #pragma unroll
    for (int off = 32; off > 0; off >>= 1)
        sum += __shfl_down(sum, off, 64);
    __shared__ float wsum[4];
    int lane = threadIdx.x & 63, wave = threadIdx.x >> 6;
    if (lane == 0) wsum[wave] = sum;
    __syncthreads();
    if (threadIdx.x == 0)
        atomicAdd(out, (wsum[0] + wsum[1] + wsum[2] + wsum[3]) * (1.0f / NPTS));
}

extern "C" void kernel_launch(void* const* d_in, const int* in_sizes, int n_in,
                              void* d_out, int out_size, void* d_ws, size_t ws_size,
                              hipStream_t stream) {
    const float* pred = (const float*)d_in[0];
    const float* targ = (const float*)d_in[1];
    float* out = (float*)d_out;
    unsigned int* mins = (unsigned int*)d_ws;
    unsigned int* counter = mins + 2 * NPTS;

    if (ws_size >= (size_t)(2 * NPTS + 1) * sizeof(unsigned int)) {
        // mins sentinel + counter sentinel in ONE memset (0x7F7F7F7F each)
        hipMemsetAsync(d_ws, 0x7F, (2 * NPTS + 1) * sizeof(unsigned int), stream);
        chamfer_pass1<true><<<GRID, BLOCK, 0, stream>>>(pred, targ, mins, counter, out);
    } else {
        hipMemsetAsync(d_ws, 0x7F, 2 * NPTS * sizeof(unsigned int), stream);
        hipMemsetAsync(d_out, 0, sizeof(float), stream);
        chamfer_pass1<false><<<GRID, BLOCK, 0, stream>>>(pred, targ, mins, counter, out);
        chamfer_pass2<<<64, 256, 0, stream>>>(mins, out);
    }
}

// Round 7
// 297.994 us; speedup vs baseline: 5.7542x; 5.7542x over previous
//
#include <hip/hip_runtime.h>

#define NPTS 32768
#define BLOCK 256
#define SPT 16                            // source points per thread
#define NSLICE 128                        // target slices per direction
#define SLICE_PTS (NPTS / NSLICE)         // 256
#define SRC_PER_BLOCK (BLOCK * SPT)       // 4096
#define SRC_CHUNKS (NPTS / SRC_PER_BLOCK) // 8
#define GRID (2 * SRC_CHUNKS * NSLICE)    // 2048 blocks -> 8 blocks/CU resident
#define SENTINEL 0x7F7F7F7Fu              // == 3.39e38f; memset pattern 0x7F
#define LASTVAL (SENTINEL + (unsigned)GRID - 1u)

// Pass 1: block = (dir, source-chunk of 4096, target-slice of 256).
// min_t |s-t|^2 = |s|^2 - 2 * max_t (s.t - |t|^2/2); qh = -|t|^2/2 staged in LDS.
// launch_bounds(256,4): VGPR=52 proven no-spill; (256,8) spilled -> 6 GB scratch (R6).
// Occupancy comes from grid=2048 + 4.6 KB LDS: 8 blocks/CU at VGPR 52.
template <bool FUSED>
__global__ __launch_bounds__(BLOCK, 4)
void chamfer_pass1(const float* __restrict__ pred,
                   const float* __restrict__ targ,
                   unsigned int* __restrict__ mins,
                   unsigned int* __restrict__ counter,
                   float* __restrict__ out) {
    __shared__ float4 sh[SLICE_PTS + 2];   // +2: prefetch overrun pad (never consumed)

    int b = blockIdx.x;
    int dir = b >> 10;             // 0: pred->target, 1: target->pred
    int rem = b & 1023;
    int slice = rem >> 3;          // 0..127
    int chunk = rem & 7;           // 0..7

    const float* src = dir ? targ : pred;
    const float* tgt = dir ? pred : targ;
    unsigned int* outm = mins + dir * NPTS;

    // stage the target slice as {x, y, z, -|t|^2/2}
    int slice_base = slice * SLICE_PTS;
    {
        int j = threadIdx.x;               // SLICE_PTS == BLOCK
        int g = slice_base + j;
        float x = tgt[3*g+0], y = tgt[3*g+1], z = tgt[3*g+2];
        sh[j] = make_float4(x, y, z, -0.5f * (x*x + y*y + z*z));
    }

    // 16 source points in registers
    float sx[SPT], sy[SPT], sz[SPT], m[SPT];
    int i_base = chunk * SRC_PER_BLOCK + threadIdx.x;
    #pragma unroll
    for (int p = 0; p < SPT; ++p) {
        int i = i_base + p * BLOCK;
        sx[p] = src[3*i+0]; sy[p] = src[3*i+1]; sz[p] = src[3*i+2];
        m[p] = -3.4e38f;
    }
    __syncthreads();

    // software-pipelined: prefetch next target pair while computing current
    float4 ca = sh[0], cb = sh[1];
    #pragma unroll 4
    for (int j = 0; j < SLICE_PTS; j += 2) {
        float4 na = sh[j+2];       // pad makes last-iter read safe
        float4 nb = sh[j+3];
        #pragma unroll
        for (int p = 0; p < SPT; ++p) {
            float ra = fmaf(sx[p], ca.x, fmaf(sy[p], ca.y, fmaf(sz[p], ca.z, ca.w)));
            float rb = fmaf(sx[p], cb.x, fmaf(sy[p], cb.y, fmaf(sz[p], cb.z, cb.w)));
            m[p] = fmaxf(m[p], fmaxf(ra, rb));   // -> v_max3_f32
        }
        ca = na; cb = nb;
    }

    #pragma unroll
    for (int p = 0; p < SPT; ++p) {
        int i = i_base + p * BLOCK;
        float q = fmaf(sx[p], sx[p], fmaf(sy[p], sy[p], sz[p]*sz[p]));
        float d = fmaxf(fmaf(-2.0f, m[p], q), 0.0f);  // exact distance >= 0
        atomicMin(&outm[i], __float_as_uint(d));      // non-neg float: uint cmp ok
    }

    if (!FUSED) return;

    // ---- fused finalization: last block reduces ----
    __threadfence();   // release our mins updates device-wide
    __shared__ unsigned int is_last;
    if (threadIdx.x == 0)
        is_last = (atomicAdd(counter, 1u) == LASTVAL) ? 1u : 0u;
    __syncthreads();
    if (is_last) {
        __threadfence();   // acquire side
        float sum = 0.0f;
        for (int i = threadIdx.x; i < 2 * NPTS; i += BLOCK) {
            unsigned int u = __hip_atomic_load(&mins[i], __ATOMIC_RELAXED,
                                               __HIP_MEMORY_SCOPE_AGENT);
            sum += __uint_as_float(u);
        }
        #pragma unroll
        for (int off = 32; off > 0; off >>= 1)
            sum += __shfl_down(sum, off, 64);
        __shared__ float wsum[4];
        int lane = threadIdx.x & 63, wave = threadIdx.x >> 6;
        if (lane == 0) wsum[wave] = sum;
        __syncthreads();
        if (threadIdx.x == 0)
            out[0] = (wsum[0] + wsum[1] + wsum[2] + wsum[3]) * (1.0f / NPTS);
    }
}

// Fallback pass 2 (only used if ws_size can't hold the counter word).
__global__ __launch_bounds__(256)
void chamfer_pass2(const unsigned int* __restrict__ mins,
                   float* __restrict__ out) {
    float sum = 0.0f;
    for (int i = blockIdx.x * blockDim.x + threadIdx.x; i < 2 * NPTS;
         i += gridDim.x * blockDim.x)
        sum += __uint_as_float(mins[i]);
    #pragma unroll
    for (int off = 32; off > 0; off >>= 1)
        sum += __shfl_down(sum, off, 64);
    __shared__ float wsum[4];
    int lane = threadIdx.x & 63, wave = threadIdx.x >> 6;
    if (lane == 0) wsum[wave] = sum;
    __syncthreads();
    if (threadIdx.x == 0)
        atomicAdd(out, (wsum[0] + wsum[1] + wsum[2] + wsum[3]) * (1.0f / NPTS));
}

extern "C" void kernel_launch(void* const* d_in, const int* in_sizes, int n_in,
                              void* d_out, int out_size, void* d_ws, size_t ws_size,
                              hipStream_t stream) {
    const float* pred = (const float*)d_in[0];
    const float* targ = (const float*)d_in[1];
    float* out = (float*)d_out;
    unsigned int* mins = (unsigned int*)d_ws;
    unsigned int* counter = mins + 2 * NPTS;

    if (ws_size >= (size_t)(2 * NPTS + 1) * sizeof(unsigned int)) {
        // mins sentinel + counter sentinel in ONE memset (0x7F7F7F7F each)
        hipMemsetAsync(d_ws, 0x7F, (2 * NPTS + 1) * sizeof(unsigned int), stream);
        chamfer_pass1<true><<<GRID, BLOCK, 0, stream>>>(pred, targ, mins, counter, out);
    } else {
        hipMemsetAsync(d_ws, 0x7F, 2 * NPTS * sizeof(unsigned int), stream);
        hipMemsetAsync(d_out, 0, sizeof(float), stream);
        chamfer_pass1<false><<<GRID, BLOCK, 0, stream>>>(pred, targ, mins, counter, out);
        chamfer_pass2<<<64, 256, 0, stream>>>(mins, out);
    }
}

// Round 8
// 284.282 us; speedup vs baseline: 6.0317x; 1.0482x over previous
//
#include <hip/hip_runtime.h>

#define NPTS 32768
#define BLOCK 256
#define SPT 16                              // source points per lane
#define TG 4                                // target reg-groups per wave (64 tgt each)
#define TGT_PER_WAVE (64 * TG)              // 256
#define SRC_PER_WAVE (64 * SPT)             // 1024
#define WAVES_PER_BLOCK (BLOCK / 64)        // 4
#define SRC_CHUNKS (NPTS / SRC_PER_WAVE)    // 32
#define TGT_SLICES (NPTS / TGT_PER_WAVE)    // 128
#define TOTAL_WAVES (2 * SRC_CHUNKS * TGT_SLICES)  // 8192
#define GRID (TOTAL_WAVES / WAVES_PER_BLOCK)       // 2048 blocks

// broadcast lane l's value to all lanes via SGPR (uniform l)
__device__ __forceinline__ float rl(float v, int l) {
    return __int_as_float(__builtin_amdgcn_readlane(__float_as_int(v), l));
}

// Each WAVE owns (dir, 1024-src chunk, 256-tgt slice). Targets live in 16 VGPRs
// as {x,y,z,qh=-|t|^2/2}; inner loop broadcasts them via v_readlane (SGPR) —
// no LDS, no syncthreads, no lgkmcnt in the hot loop. Pure VALU.
// min_t |s-t|^2 = |s|^2 - 2*max_t(s.t - |t|^2/2).
__global__ __launch_bounds__(BLOCK, 4)
void chamfer_pass1(const float* __restrict__ pred,
                   const float* __restrict__ targ,
                   unsigned int* __restrict__ mins) {
    int wid = blockIdx.x * WAVES_PER_BLOCK + (threadIdx.x >> 6);
    int lane = threadIdx.x & 63;
    int dir = wid >> 12;             // 4096 waves per dir
    int rem = wid & 4095;
    int chunk = rem >> 7;            // 0..31
    int slice = rem & 127;           // 0..127

    const float* src = dir ? targ : pred;
    const float* tgt = dir ? pred : targ;
    unsigned int* outm = mins + dir * NPTS;

    // wave-private targets: lane holds TG targets {x,y,z,qh}
    float tx[TG], ty[TG], tz[TG], tw[TG];
    #pragma unroll
    for (int k = 0; k < TG; ++k) {
        int g = slice * TGT_PER_WAVE + k * 64 + lane;
        float x = tgt[3*g+0], y = tgt[3*g+1], z = tgt[3*g+2];
        tx[k] = x; ty[k] = y; tz[k] = z;
        tw[k] = -0.5f * fmaf(x, x, fmaf(y, y, z * z));
    }

    // 16 source points in registers
    float sx[SPT], sy[SPT], sz[SPT], m[SPT];
    int i_base = chunk * SRC_PER_WAVE + lane;
    #pragma unroll
    for (int p = 0; p < SPT; ++p) {
        int i = i_base + p * 64;
        sx[p] = src[3*i+0]; sy[p] = src[3*i+1]; sz[p] = src[3*i+2];
        m[p] = -3.4e38f;
    }

    // hot loop: 2 targets per step, broadcast via readlane
    #pragma unroll
    for (int k = 0; k < TG; ++k) {
        float gx = tx[k], gy = ty[k], gz = tz[k], gw = tw[k];
        #pragma unroll 4
        for (int l = 0; l < 64; l += 2) {
            float ax = rl(gx, l),   ay = rl(gy, l);
            float az = rl(gz, l),   aw = rl(gw, l);
            float bx = rl(gx, l+1), by = rl(gy, l+1);
            float bz = rl(gz, l+1), bw = rl(gw, l+1);
            #pragma unroll
            for (int p = 0; p < SPT; ++p) {
                float ra = fmaf(sx[p], ax, fmaf(sy[p], ay, fmaf(sz[p], az, aw)));
                float rb = fmaf(sx[p], bx, fmaf(sy[p], by, fmaf(sz[p], bz, bw)));
                m[p] = fmaxf(m[p], fmaxf(ra, rb));   // -> v_max3_f32
            }
        }
    }

    #pragma unroll
    for (int p = 0; p < SPT; ++p) {
        int i = i_base + p * 64;
        float q = fmaf(sx[p], sx[p], fmaf(sy[p], sy[p], sz[p]*sz[p]));
        float d = fmaxf(fmaf(-2.0f, m[p], q), 0.0f);  // exact distance >= 0
        atomicMin(&outm[i], __float_as_uint(d));      // non-neg float: uint cmp ok
    }
}

// Pass 2: sum all 65536 per-point mins; out = sum / 32768 (= mean1 + mean2).
__global__ __launch_bounds__(256)
void chamfer_pass2(const unsigned int* __restrict__ mins,
                   float* __restrict__ out) {
    float sum = 0.0f;
    for (int i = blockIdx.x * blockDim.x + threadIdx.x; i < 2 * NPTS;
         i += gridDim.x * blockDim.x)
        sum += __uint_as_float(mins[i]);
    #pragma unroll
    for (int off = 32; off > 0; off >>= 1)
        sum += __shfl_down(sum, off, 64);
    __shared__ float wsum[4];
    int lane = threadIdx.x & 63, wave = threadIdx.x >> 6;
    if (lane == 0) wsum[wave] = sum;
    __syncthreads();
    if (threadIdx.x == 0)
        atomicAdd(out, (wsum[0] + wsum[1] + wsum[2] + wsum[3]) * (1.0f / NPTS));
}

extern "C" void kernel_launch(void* const* d_in, const int* in_sizes, int n_in,
                              void* d_out, int out_size, void* d_ws, size_t ws_size,
                              hipStream_t stream) {
    const float* pred = (const float*)d_in[0];
    const float* targ = (const float*)d_in[1];
    float* out = (float*)d_out;
    unsigned int* mins = (unsigned int*)d_ws;

    // sentinel 0x7F7F7F7F == 3.39e38f in every ws float
    hipMemsetAsync(d_ws, 0x7F, 2 * NPTS * sizeof(unsigned int), stream);
    hipMemsetAsync(d_out, 0, sizeof(float), stream);

    chamfer_pass1<<<GRID, BLOCK, 0, stream>>>(pred, targ, mins);
    chamfer_pass2<<<64, 256, 0, stream>>>(mins, out);
}

// Round 9
// 218.399 us; speedup vs baseline: 7.8513x; 1.3017x over previous
//
#include <hip/hip_runtime.h>

#define NPTS 32768
#define BLOCK 256
#define SPT 16                            // source points per thread
#define NSLICE 64                         // target slices per direction
#define SLICE_PTS (NPTS / NSLICE)         // 512
#define SRC_PER_BLOCK (BLOCK * SPT)       // 4096
#define SRC_CHUNKS (NPTS / SRC_PER_BLOCK) // 8
#define GRID (2 * SRC_CHUNKS * NSLICE)    // 1024 blocks -> 4 blocks/CU, 16 waves/CU

// Pass 1: block = (dir, source-chunk of 4096, target-slice of 512). R4 structure
// (best known: 168 us) + wave-phase desync: each wave starts its tile sweep at a
// different offset so the per-unroll-body ds_read bursts from the CU's 16 waves
// hit the LDS pipe at 4 different phases instead of convoying after the barrier.
// min_t |s-t|^2 = |s|^2 - 2 * max_t (s.t - |t|^2/2); qh = -|t|^2/2 staged in LDS.
__global__ __launch_bounds__(BLOCK, 4)
void chamfer_pass1(const float* __restrict__ pred,
                   const float* __restrict__ targ,
                   unsigned int* __restrict__ mins) {
    __shared__ float4 sh[SLICE_PTS + 2];   // +2: prefetch overrun pad (never consumed)

    int b = blockIdx.x;
    int dir = b >> 9;              // 0: pred->target, 1: target->pred
    int rem = b & 511;
    int slice = rem >> 3;          // 0..63
    int chunk = rem & 7;           // 0..7

    const float* src = dir ? targ : pred;
    const float* tgt = dir ? pred : targ;
    unsigned int* outm = mins + dir * NPTS;

    // stage the target slice as {x, y, z, -|t|^2/2}
    int slice_base = slice * SLICE_PTS;
    #pragma unroll
    for (int k = 0; k < SLICE_PTS / BLOCK; ++k) {
        int j = threadIdx.x + k * BLOCK;
        int g = slice_base + j;
        float x = tgt[3*g+0], y = tgt[3*g+1], z = tgt[3*g+2];
        sh[j] = make_float4(x, y, z, -0.5f * (x*x + y*y + z*z));
    }

    // 16 source points in registers
    float sx[SPT], sy[SPT], sz[SPT], m[SPT];
    int i_base = chunk * SRC_PER_BLOCK + threadIdx.x;
    #pragma unroll
    for (int p = 0; p < SPT; ++p) {
        int i = i_base + p * BLOCK;
        sx[p] = src[3*i+0]; sy[p] = src[3*i+1]; sz[p] = src[3*i+2];
        m[p] = -3.4e38f;
    }
    __syncthreads();

    // per-wave start phase: waves of this CU sweep the tile at 4 distinct offsets
    int wave = threadIdx.x >> 6;
    int j0 = ((b + wave) & 3) << 7;        // 0,128,256,384 (targets, even)

    // segment A: [j0, SLICE_PTS), software-pipelined rotation (R4-proven)
    float4 ca = sh[j0], cb = sh[j0 + 1];
    #pragma unroll 4
    for (int j = j0; j < SLICE_PTS; j += 2) {
        float4 na = sh[j+2];       // pad makes last-iter read safe
        float4 nb = sh[j+3];
        #pragma unroll
        for (int p = 0; p < SPT; ++p) {
            float ra = fmaf(sx[p], ca.x, fmaf(sy[p], ca.y, fmaf(sz[p], ca.z, ca.w)));
            float rb = fmaf(sx[p], cb.x, fmaf(sy[p], cb.y, fmaf(sz[p], cb.z, cb.w)));
            m[p] = fmaxf(m[p], fmaxf(ra, rb));   // -> v_max3_f32
        }
        ca = na; cb = nb;
    }
    // segment B: [0, j0)
    ca = sh[0]; cb = sh[1];
    #pragma unroll 4
    for (int j = 0; j < j0; j += 2) {
        float4 na = sh[j+2];
        float4 nb = sh[j+3];
        #pragma unroll
        for (int p = 0; p < SPT; ++p) {
            float ra = fmaf(sx[p], ca.x, fmaf(sy[p], ca.y, fmaf(sz[p], ca.z, ca.w)));
            float rb = fmaf(sx[p], cb.x, fmaf(sy[p], cb.y, fmaf(sz[p], cb.z, cb.w)));
            m[p] = fmaxf(m[p], fmaxf(ra, rb));
        }
        ca = na; cb = nb;
    }

    #pragma unroll
    for (int p = 0; p < SPT; ++p) {
        int i = i_base + p * BLOCK;
        float q = fmaf(sx[p], sx[p], fmaf(sy[p], sy[p], sz[p]*sz[p]));
        float d = fmaxf(fmaf(-2.0f, m[p], q), 0.0f);  // exact distance >= 0
        atomicMin(&outm[i], __float_as_uint(d));      // non-neg float: uint cmp ok
    }
}

// Pass 2: sum all 65536 per-point mins; out = sum / 32768 (= mean1 + mean2).
__global__ __launch_bounds__(256)
void chamfer_pass2(const unsigned int* __restrict__ mins,
                   float* __restrict__ out) {
    float sum = 0.0f;
    for (int i = blockIdx.x * blockDim.x + threadIdx.x; i < 2 * NPTS;
         i += gridDim.x * blockDim.x)
        sum += __uint_as_float(mins[i]);
    #pragma unroll
    for (int off = 32; off > 0; off >>= 1)
        sum += __shfl_down(sum, off, 64);
    __shared__ float wsum[4];
    int lane = threadIdx.x & 63, wave = threadIdx.x >> 6;
    if (lane == 0) wsum[wave] = sum;
    __syncthreads();
    if (threadIdx.x == 0)
        atomicAdd(out, (wsum[0] + wsum[1] + wsum[2] + wsum[3]) * (1.0f / NPTS));
}

extern "C" void kernel_launch(void* const* d_in, const int* in_sizes, int n_in,
                              void* d_out, int out_size, void* d_ws, size_t ws_size,
                              hipStream_t stream) {
    const float* pred = (const float*)d_in[0];
    const float* targ = (const float*)d_in[1];
    float* out = (float*)d_out;
    unsigned int* mins = (unsigned int*)d_ws;

    // sentinel 0x7F7F7F7F == 3.39e38f in every ws float
    hipMemsetAsync(d_ws, 0x7F, 2 * NPTS * sizeof(unsigned int), stream);
    hipMemsetAsync(d_out, 0, sizeof(float), stream);

    chamfer_pass1<<<GRID, BLOCK, 0, stream>>>(pred, targ, mins);
    chamfer_pass2<<<64, 256, 0, stream>>>(mins, out);
}